// Round 2
// 161.787 us; speedup vs baseline: 1.0135x; 1.0135x over previous
//
#include <hip/hip_runtime.h>
#include <math.h>

#define SIGMA_BOOST 2.0f
#define EPSILON 1e-6f

// native clang vector type — required for __builtin_nontemporal_load/store
// (HIP's float4 is a struct and the builtin rejects it)
typedef float vfloat4 __attribute__((ext_vector_type(4)));

// ---------------------------------------------------------------------------
// Pre-pass: per-t parameters -> float4 {mean_row, mean_col, sigma, pvalue}
//   mean  = sigmoid(pmean) * (N-1)
//   sigma = (softplus(psigma + SIGMA_BOOST) + EPS) * N
// softplus via stable logaddexp(x,0) = max(x,0) + log1p(exp(-|x|)) to match
// numpy's formulation. Plain expf/log1pf (accurate, ~1 ulp) to minimize
// round-boundary index flips vs the reference.
// ---------------------------------------------------------------------------
__global__ void params_kernel(const float2* __restrict__ pmeans,
                              const float* __restrict__ psigmas,
                              const float* __restrict__ pvalues,
                              float4* __restrict__ params, int N) {
    int t = blockIdx.x * blockDim.x + threadIdx.x;
    if (t >= N) return;
    float2 pm = pmeans[t];
    float scale = (float)(N - 1);
    float m0 = __fmul_rn(__fdiv_rn(1.0f, __fadd_rn(1.0f, expf(-pm.x))), scale);
    float m1 = __fmul_rn(__fdiv_rn(1.0f, __fadd_rn(1.0f, expf(-pm.y))), scale);
    float z  = __fadd_rn(psigmas[t], SIGMA_BOOST);
    float sp = __fadd_rn(fmaxf(z, 0.0f), log1pf(expf(-fabsf(z))));
    float sg = __fmul_rn(__fadd_rn(sp, EPSILON), (float)N);
    params[t] = make_float4(m0, m1, sg, pvalues[t]);
}

// ---------------------------------------------------------------------------
// One block per batch row b. 64 KB LDS accumulator holds the whole y-row.
// Latency-bound fix: batch 4 t's per loop step so each thread keeps 4
// independent  noise->col->x[col]->ds_add  chains in flight instead of 1.
// Noise is loaded as 16B nontemporal (streaming; don't evict the x-row from
// L1/L2). __launch_bounds__(1024,8) caps VGPRs at 64 so the LDS-capped
// 2 blocks/CU (32 waves/CU) residency is preserved. Per-t arithmetic is
// bit-identical to the previous verified version.
// ---------------------------------------------------------------------------
template <bool INLINE_PARAMS>
__launch_bounds__(1024, 8)
__global__ void contract_kernel(const float* __restrict__ x,
                                const float2* __restrict__ noise,
                                const float4* __restrict__ params,
                                const float2* __restrict__ pmeans,
                                const float* __restrict__ psigmas,
                                const float* __restrict__ pvalues,
                                float* __restrict__ y, int N) {
    extern __shared__ float ly[];
    const int b = blockIdx.x;
    const int tid = threadIdx.x;
    const int nthr = blockDim.x;

    // zero LDS accumulator (vectorized)
    float4* ly4 = (float4*)ly;
    const int n4 = N >> 2;
    for (int i = tid; i < n4; i += nthr) ly4[i] = make_float4(0.f, 0.f, 0.f, 0.f);
    __syncthreads();

    const float* xb = x + (size_t)b * N;
    const float fN1 = (float)(N - 1);

    if (!INLINE_PARAMS && (N % (4 * nthr)) == 0) {
        // ---- fast path: 4 t's (2 x 16B noise loads) per step ---------------
        const vfloat4* nb4 = (const vfloat4*)(noise + (size_t)b * N);  // N/2 vecs
        const int npairs = N >> 1;
        for (int base = 0; base < npairs; base += 2 * nthr) {
            const int p0 = base + tid;
            const int p1 = base + nthr + tid;
            // streaming loads: address-independent, all issue before any use
            vfloat4 nz0 = __builtin_nontemporal_load(&nb4[p0]);
            vfloat4 nz1 = __builtin_nontemporal_load(&nb4[p1]);
            float4 pa = params[2 * p0];
            float4 pb = params[2 * p0 + 1];
            float4 pc = params[2 * p1];
            float4 pd = params[2 * p1 + 1];

            // sample = mean + sigma*noise, deliberately UNFUSED (rounding
            // must match numpy's separate mul+add).
            float sA0 = __fadd_rn(pa.x, __fmul_rn(pa.z, nz0.x));
            float sA1 = __fadd_rn(pa.y, __fmul_rn(pa.z, nz0.y));
            float sB0 = __fadd_rn(pb.x, __fmul_rn(pb.z, nz0.z));
            float sB1 = __fadd_rn(pb.y, __fmul_rn(pb.z, nz0.w));
            float sC0 = __fadd_rn(pc.x, __fmul_rn(pc.z, nz1.x));
            float sC1 = __fadd_rn(pc.y, __fmul_rn(pc.z, nz1.y));
            float sD0 = __fadd_rn(pd.x, __fmul_rn(pd.z, nz1.z));
            float sD1 = __fadd_rn(pd.y, __fmul_rn(pd.z, nz1.w));

            // np.round = half-to-even = rintf; clamp in float, exact int cvt
            int rA = (int)fminf(fmaxf(rintf(sA0), 0.0f), fN1);
            int cA = (int)fminf(fmaxf(rintf(sA1), 0.0f), fN1);
            int rB = (int)fminf(fmaxf(rintf(sB0), 0.0f), fN1);
            int cB = (int)fminf(fmaxf(rintf(sB1), 0.0f), fN1);
            int rC = (int)fminf(fmaxf(rintf(sC0), 0.0f), fN1);
            int cC = (int)fminf(fmaxf(rintf(sC1), 0.0f), fN1);
            int rD = (int)fminf(fmaxf(rintf(sD0), 0.0f), fN1);
            int cD = (int)fminf(fmaxf(rintf(sD1), 0.0f), fN1);

            // 4 independent gathers in flight
            float xA = xb[cA];
            float xB = xb[cB];
            float xC = xb[cC];
            float xD = xb[cD];

            // fire-and-forget LDS atomics (no result dependency)
            atomicAdd(&ly[rA], __fmul_rn(pa.w, xA));
            atomicAdd(&ly[rB], __fmul_rn(pb.w, xB));
            atomicAdd(&ly[rC], __fmul_rn(pc.w, xC));
            atomicAdd(&ly[rD], __fmul_rn(pd.w, xD));
        }
    } else {
        // ---- generic / inline-params fallback (original serial loop) -------
        const float2* nb = noise + (size_t)b * N;
        for (int t = tid; t < N; t += nthr) {
            float m0, m1, sg, pv;
            if (INLINE_PARAMS) {
                float2 pm = pmeans[t];
                float scale = (float)(N - 1);
                m0 = __fmul_rn(__fdiv_rn(1.0f, __fadd_rn(1.0f, expf(-pm.x))), scale);
                m1 = __fmul_rn(__fdiv_rn(1.0f, __fadd_rn(1.0f, expf(-pm.y))), scale);
                float z  = __fadd_rn(psigmas[t], SIGMA_BOOST);
                float sp = __fadd_rn(fmaxf(z, 0.0f), log1pf(expf(-fabsf(z))));
                sg = __fmul_rn(__fadd_rn(sp, EPSILON), (float)N);
                pv = pvalues[t];
            } else {
                float4 p = params[t];
                m0 = p.x; m1 = p.y; sg = p.z; pv = p.w;
            }
            float2 nz = nb[t];
            float s0 = __fadd_rn(m0, __fmul_rn(sg, nz.x));
            float s1 = __fadd_rn(m1, __fmul_rn(sg, nz.y));
            int row = (int)fminf(fmaxf(rintf(s0), 0.0f), fN1);
            int col = (int)fminf(fmaxf(rintf(s1), 0.0f), fN1);
            float contrib = __fmul_rn(pv, xb[col]);
            atomicAdd(&ly[row], contrib);
        }
    }
    __syncthreads();

    // coalesced write-out of the full row (nontemporal: y is never re-read)
    const vfloat4* lv4 = (const vfloat4*)ly;
    vfloat4* yb4 = (vfloat4*)(y + (size_t)b * N);
    for (int i = tid; i < n4; i += nthr)
        __builtin_nontemporal_store(lv4[i], &yb4[i]);
}

extern "C" void kernel_launch(void* const* d_in, const int* in_sizes, int n_in,
                              void* d_out, int out_size, void* d_ws, size_t ws_size,
                              hipStream_t stream) {
    const float*  x       = (const float*)d_in[0];
    const float2* noise   = (const float2*)d_in[1];
    const float2* pmeans  = (const float2*)d_in[2];
    const float*  psigmas = (const float*)d_in[3];
    const float*  pvalues = (const float*)d_in[4];
    float* y = (float*)d_out;

    const int N = in_sizes[3];          // psigmas is (N,)
    const int B = in_sizes[0] / N;      // x is (B,N)

    const size_t params_bytes = (size_t)N * sizeof(float4);
    const bool use_ws = (ws_size >= params_bytes) && (d_ws != nullptr);

    const int block = 1024;
    const size_t lds_bytes = (size_t)N * sizeof(float);  // 64 KB at N=16384

    if (use_ws) {
        float4* params = (float4*)d_ws;
        params_kernel<<<(N + 255) / 256, 256, 0, stream>>>(pmeans, psigmas,
                                                           pvalues, params, N);
        contract_kernel<false><<<B, block, lds_bytes, stream>>>(
            x, noise, params, nullptr, nullptr, nullptr, y, N);
    } else {
        contract_kernel<true><<<B, block, lds_bytes, stream>>>(
            x, noise, nullptr, pmeans, psigmas, pvalues, y, N);
    }
}